// Round 10
// baseline (229.820 us; speedup 1.0000x reference)
//
#include <hip/hip_runtime.h>
#include <math.h>

// CIN (xDeepFM) — split-bf16 16x16x32 MFMA, 2 batches/block, 3-deep chunk
// prefetch + 1-deep REGISTER prefetch of A-fragments and x-scales.
// y[b,o,d] = bias[o] + sum_f x[b,f,d] * ( sum_h W[o,f*H+h] * h_in[b,h,d] )
//   W*h ~= Whi*hhi + Whi*hlo + Wlo*hhi   (split bf16, lo*lo dropped)
// Per iteration c: gll-prefetch chunk c+3; vmcnt(2*SR) ensures chunk c+1 is in
// LDS; ds_read A(c+1)+scales(c+1) into ping-pong reg slots (no wait — latency
// hides under this iteration's MFMAs, which consume A(c) from registers with
// NO LDS dependency). Wave-private staging -> no hot-loop barriers.
// B=512, F=32, D=64, O=128; H0=32 (h=x), H1=H2=128.

typedef __attribute__((ext_vector_type(8))) short bf16x8;
typedef __attribute__((ext_vector_type(4))) float f32x4;
typedef __attribute__((ext_vector_type(4))) unsigned short u16x4;

#define HT_LO 4194304   // shorts: 512*64*128 (offset of lo plane)

__device__ __forceinline__ unsigned short f2bf(float f) {
  unsigned int u = __float_as_uint(f);
  u = (u + 0x7fffu + ((u >> 16) & 1u)) >> 16;   // RNE
  return (unsigned short)u;
}
__device__ __forceinline__ float bf2f(unsigned short h) {
  return __uint_as_float((unsigned int)h << 16);
}

__device__ __forceinline__ void gll16(const void* g, void* l) {
  __builtin_amdgcn_global_load_lds(
      (const __attribute__((address_space(1))) unsigned int*)g,
      (__attribute__((address_space(3))) unsigned int*)l, 16, 0, 0);
}

// ---- pre-pass: repack W (fp32, row-major 128xK) into split-bf16 image,
// chunk-sequential in ITERATION order: chunk c = pass*32 + f at offset c*CHUNK.
// in-chunk (16B units): [s in {hi,lo}][ksl][idx = mt*64 + lane]
// element: W[o = mt*16+(l&15)][kcol = f*H + pass*(KSP*32) + ksl*32 + (l>>4)*8 + j]
__global__ void repack_w_kernel(const float* __restrict__ W, unsigned short* __restrict__ dst,
                                int H, int KSP, int nthreads)
{
  const int t = blockIdx.x * 256 + threadIdx.x;
  if (t >= nthreads) return;
  const int K = 32 * H;
  const int idx = t & 511;
  const int ksl = (t >> 9) % KSP;
  const int c   = (t >> 9) / KSP;
  const int pass = c >> 5, f = c & 31;
  const int mt = idx >> 6, l = idx & 63;
  const int o = mt * 16 + (l & 15);
  const int kcol = f * H + pass * (KSP * 32) + ksl * 32 + (l >> 4) * 8;
  const float* s = W + (size_t)o * K + kcol;
  u16x4 h0, h1, l0, l1;
#pragma unroll
  for (int j = 0; j < 4; ++j) {
    float v = s[j];
    unsigned short hb = f2bf(v);
    h0[j] = hb; l0[j] = f2bf(v - bf2f(hb));
    v = s[4 + j];
    hb = f2bf(v);
    h1[j] = hb; l1[j] = f2bf(v - bf2f(hb));
  }
  const size_t CU16 = (size_t)2 * KSP * 512;       // 16B units per chunk
  const size_t uhi = (size_t)c * CU16 + (size_t)(0 * KSP + ksl) * 512 + idx;
  const size_t ulo = (size_t)c * CU16 + (size_t)(1 * KSP + ksl) * 512 + idx;
  *(u16x4*)(dst + uhi * 8)     = h0;
  *(u16x4*)(dst + uhi * 8 + 4) = h1;
  *(u16x4*)(dst + ulo * 8)     = l0;
  *(u16x4*)(dst + ulo * 8 + 4) = l1;
}

// one stage: prefetch chunk C+3 -> counted wait (chunk C+1 landed) ->
// reg-read A(C+1)/scales(C+1) (no wait) -> MFMA with A(C) regs -> Y update.
#define BODY(C, BUF, DOPREF, WAITN, DOREAD)                                                \
  {                                                                                        \
    if (DOPREF) {                                                                          \
      const char* psrc = (const char*)Wimg + (size_t)((C) + 3) * CHUNK;                    \
      _Pragma("unroll")                                                                    \
      for (int r = 0; r < SR; ++r)                                                         \
        gll16(psrc + (size_t)(r * 512 + tid) * 16,                                         \
              lds + (((BUF) + 3) & 3) * CHUNK + (r * 512 + w * 64) * 16);                  \
    }                                                                                      \
    asm volatile("s_waitcnt vmcnt(%0)" :: "i"(WAITN) : "memory");                          \
    if (DOREAD) {                                                                          \
      const char* nb = lds + (((BUF) + 1) & 3) * CHUNK;                                    \
      _Pragma("unroll")                                                                    \
      for (int ks = 0; ks < KSP; ++ks) {                                                   \
        AH[((BUF) + 1) & 1][ks] = *(const bf16x8*)(nb + (((0 * KSP + ks) * 8 + w) * 64 + l) * 16); \
        AL[((BUF) + 1) & 1][ks] = *(const bf16x8*)(nb + (((1 * KSP + ks) * 8 + w) * 64 + l) * 16); \
      }                                                                                    \
      const int f1_ = ((C) + 1) & 31;                                                      \
      _Pragma("unroll")                                                                    \
      for (int nt = 0; nt < 4; ++nt) {                                                     \
        S0v[((BUF) + 1) & 1][nt] = lx0[f1_ * 64 + nt * 16 + li];                           \
        S1v[((BUF) + 1) & 1][nt] = lx1[f1_ * 64 + nt * 16 + li];                           \
      }                                                                                    \
    }                                                                                      \
    f32x4 G0[4], G1[4];                                                                    \
    __builtin_amdgcn_s_setprio(1);                                                         \
    _Pragma("unroll")                                                                      \
    for (int ks = 0; ks < KSP; ++ks) {                                                     \
      const bf16x8 Ah = AH[(BUF) & 1][ks];                                                 \
      const bf16x8 Al = AL[(BUF) & 1][ks];                                                 \
      _Pragma("unroll")                                                                    \
      for (int nt = 0; nt < 4; ++nt) {                                                     \
        G0[nt] = __builtin_amdgcn_mfma_f32_16x16x32_bf16(Ah, Bh0[ks][nt],                  \
                     (ks == 0) ? zero4 : G0[nt], 0, 0, 0);                                 \
        G1[nt] = __builtin_amdgcn_mfma_f32_16x16x32_bf16(Ah, Bh1[ks][nt],                  \
                     (ks == 0) ? zero4 : G1[nt], 0, 0, 0);                                 \
        G0[nt] = __builtin_amdgcn_mfma_f32_16x16x32_bf16(Ah, Bl0[ks][nt], G0[nt], 0, 0, 0);\
        G1[nt] = __builtin_amdgcn_mfma_f32_16x16x32_bf16(Ah, Bl1[ks][nt], G1[nt], 0, 0, 0);\
        G0[nt] = __builtin_amdgcn_mfma_f32_16x16x32_bf16(Al, Bh0[ks][nt], G0[nt], 0, 0, 0);\
        G1[nt] = __builtin_amdgcn_mfma_f32_16x16x32_bf16(Al, Bh1[ks][nt], G1[nt], 0, 0, 0);\
      }                                                                                    \
    }                                                                                      \
    __builtin_amdgcn_s_setprio(0);                                                         \
    _Pragma("unroll")                                                                      \
    for (int nt = 0; nt < 4; ++nt) {                                                       \
      Y0[nt] += G0[nt] * S0v[(BUF) & 1][nt];                                               \
      Y1[nt] += G1[nt] * S1v[(BUF) & 1][nt];                                               \
    }                                                                                      \
  }

// ---- main layer kernel ----
// grid 256 x 512 threads; block handles b0=2*blk, b0+1. Wave w owns o in [16w,16w+16).
// LDS: [0, 4*CHUNK) = 4-buffer chunk ring; [4*CHUNK, +16KB) = raw x[b0], x[b0+1].
template<int H, int NPASS, int KSP, bool FIRST, bool STORE_H>
__global__ __launch_bounds__(512, 2) void cin_mfma_layer(
    const unsigned short* __restrict__ Wimg,
    const float* __restrict__ x,               // (B,32,64) fp32
    const unsigned short* __restrict__ hTin,   // hi plane; lo at +HT_LO  (null if FIRST)
    const float* __restrict__ bias,
    unsigned short* __restrict__ hTout,        // hi plane; lo at +HT_LO
    float* __restrict__ outs, int col_off)
{
  constexpr int CHUNK = 2 * KSP * 8192;        // bytes per chunk (hi+lo)
  constexpr int SR = 2 * KSP;                  // gll rounds per chunk
  constexpr int NIT = NPASS * 32;
  constexpr int XOFF = 4 * CHUNK;
  __shared__ char lds[XOFF + 16384];
  const int tid = threadIdx.x;
  const int w = tid >> 6, l = tid & 63, g = l >> 4, li = l & 15;
  const int b0 = blockIdx.x * 2;
  const float* lx0 = (const float*)(lds + XOFF);
  const float* lx1 = (const float*)(lds + XOFF + 8192);

  // prologue: stage x[b0], x[b0+1] (2 gll) + chunks 0,1,2 (3*SR gll)
#pragma unroll
  for (int r = 0; r < 2; ++r)
    gll16(x + (size_t)(b0 + r) * 2048 + tid * 4, lds + XOFF + r * 8192 + w * 1024);
#pragma unroll
  for (int c = 0; c < 3; ++c) {
    const char* src = (const char*)Wimg + (size_t)c * CHUNK;
#pragma unroll
    for (int r = 0; r < SR; ++r)
      gll16(src + (size_t)(r * 512 + tid) * 16,
            lds + c * CHUNK + (r * 512 + w * 64) * 16);
  }

  f32x4 Y0[4], Y1[4];
#pragma unroll
  for (int nt = 0; nt < 4; ++nt) {
    Y0[nt] = (f32x4){0.f, 0.f, 0.f, 0.f};
    Y1[nt] = (f32x4){0.f, 0.f, 0.f, 0.f};
  }
  const f32x4 zero4 = (f32x4){0.f, 0.f, 0.f, 0.f};
  bf16x8 Bh0[KSP][4], Bl0[KSP][4], Bh1[KSP][4], Bl1[KSP][4];
  bf16x8 AH[2][KSP], AL[2][KSP];     // ping-pong A-fragment slots (slot = c&1)
  float S0v[2][4], S1v[2][4];        // ping-pong x-scale slots

  // the ONLY barrier: x-tiles (oldest 2 loads) complete -> publish to all waves
  asm volatile("s_waitcnt vmcnt(%0)" :: "i"(3 * SR) : "memory");
  __builtin_amdgcn_s_barrier();

  if constexpr (FIRST) {
    // build split B-fragments from raw x in LDS (h == x; NPASS==1, KSP==1)
#pragma unroll
    for (int nt = 0; nt < 4; ++nt) {
      union { bf16x8 v; unsigned short u[8]; } th0, tl0, th1, tl1;
#pragma unroll
      for (int j = 0; j < 8; ++j) {
        const float x0 = lx0[(g * 8 + j) * 64 + nt * 16 + li];
        const float x1 = lx1[(g * 8 + j) * 64 + nt * 16 + li];
        unsigned short hb = f2bf(x0);
        th0.u[j] = hb; tl0.u[j] = f2bf(x0 - bf2f(hb));
        hb = f2bf(x1);
        th1.u[j] = hb; tl1.u[j] = f2bf(x1 - bf2f(hb));
      }
      Bh0[0][nt] = th0.v; Bl0[0][nt] = tl0.v;
      Bh1[0][nt] = th1.v; Bl1[0][nt] = tl1.v;
    }
  }

  // pre-read A(0) and scales(0) into slot 0 (chunk 0 landed after vmcnt(2*SR))
  asm volatile("s_waitcnt vmcnt(%0)" :: "i"(2 * SR) : "memory");
#pragma unroll
  for (int ks = 0; ks < KSP; ++ks) {
    AH[0][ks] = *(const bf16x8*)(lds + (((0 * KSP + ks) * 8 + w) * 64 + l) * 16);
    AL[0][ks] = *(const bf16x8*)(lds + (((1 * KSP + ks) * 8 + w) * 64 + l) * 16);
  }
#pragma unroll
  for (int nt = 0; nt < 4; ++nt) {
    S0v[0][nt] = lx0[nt * 16 + li];
    S1v[0][nt] = lx1[nt * 16 + li];
  }

  for (int pass = 0; pass < NPASS; ++pass) {
    if constexpr (!FIRST) {
      // B-fragments for this pass, both batches (reused across all 32 f)
#pragma unroll
      for (int ks = 0; ks < KSP; ++ks)
#pragma unroll
        for (int nt = 0; nt < 4; ++nt) {
          const size_t co = (size_t)(nt * 16 + li) * 128 + pass * (KSP * 32) + ks * 32 + g * 8;
          const size_t o0 = (size_t)b0 * 8192 + co;
          const size_t o1 = (size_t)(b0 + 1) * 8192 + co;
          Bh0[ks][nt] = *(const bf16x8*)(hTin + o0);
          Bl0[ks][nt] = *(const bf16x8*)(hTin + HT_LO + o0);
          Bh1[ks][nt] = *(const bf16x8*)(hTin + o1);
          Bl1[ks][nt] = *(const bf16x8*)(hTin + HT_LO + o1);
        }
    }
    const int cb = pass * 32;
    const int fomax = (pass == NPASS - 1) ? 28 : 32;
#pragma unroll 1
    for (int fo = 0; fo < fomax; fo += 4) {
      BODY(cb + fo + 0, 0, true, 2 * SR, true)
      BODY(cb + fo + 1, 1, true, 2 * SR, true)
      BODY(cb + fo + 2, 2, true, 2 * SR, true)
      BODY(cb + fo + 3, 3, true, 2 * SR, true)
    }
  }
  // tail: last 4 chunks; waits ensure chunk C+1 in LDS before its reg-read
  BODY(NIT - 4, 0, true,  2 * SR, true)   // issues chunk NIT-1 into buf 3
  BODY(NIT - 3, 1, false, 1 * SR, true)
  BODY(NIT - 2, 2, false, 0,      true)
  BODY(NIT - 1, 3, false, 0,      false)

  // ---- epilogue: bias, split-hT stores, outs row-sums (both batches) ----
  const f32x4 bv = *(const f32x4*)(bias + w * 16 + g * 4);
#pragma unroll
  for (int nt = 0; nt < 4; ++nt) { Y0[nt] += bv; Y1[nt] += bv; }

  if constexpr (STORE_H) {
#pragma unroll
    for (int nt = 0; nt < 4; ++nt) {
      const int d = nt * 16 + li;
      u16x4 ph0, pl0, ph1, pl1;
#pragma unroll
      for (int j = 0; j < 4; ++j) {
        unsigned short hb = f2bf(Y0[nt][j]);
        ph0[j] = hb; pl0[j] = f2bf(Y0[nt][j] - bf2f(hb));
        hb = f2bf(Y1[nt][j]);
        ph1[j] = hb; pl1[j] = f2bf(Y1[nt][j] - bf2f(hb));
      }
      const size_t co = (size_t)d * 128 + w * 16 + g * 4;
      const size_t o0 = (size_t)b0 * 8192 + co;
      const size_t o1 = (size_t)(b0 + 1) * 8192 + co;
      *(u16x4*)(hTout + o0)         = ph0;
      *(u16x4*)(hTout + HT_LO + o0) = pl0;
      *(u16x4*)(hTout + o1)         = ph1;
      *(u16x4*)(hTout + HT_LO + o1) = pl1;
    }
  }

  {
    f32x4 s0 = Y0[0] + Y0[1] + Y0[2] + Y0[3];
    f32x4 s1 = Y1[0] + Y1[1] + Y1[2] + Y1[3];
#pragma unroll
    for (int m = 1; m < 16; m <<= 1) {
      s0.x += __shfl_xor(s0.x, m, 16); s0.y += __shfl_xor(s0.y, m, 16);
      s0.z += __shfl_xor(s0.z, m, 16); s0.w += __shfl_xor(s0.w, m, 16);
      s1.x += __shfl_xor(s1.x, m, 16); s1.y += __shfl_xor(s1.y, m, 16);
      s1.z += __shfl_xor(s1.z, m, 16); s1.w += __shfl_xor(s1.w, m, 16);
    }
    if (li == 0) {
      *(f32x4*)(outs + (size_t)b0 * 384 + col_off + w * 16 + g * 4)       = s0;
      *(f32x4*)(outs + (size_t)(b0 + 1) * 384 + col_off + w * 16 + g * 4) = s1;
    }
  }
}

// ---- final: out[b] = sigmoid( relu(outs[b,:]) . Wout + bout ) ----
__global__ __launch_bounds__(64) void cin_final_kernel(
    const float* __restrict__ outs, const float* __restrict__ Wout,
    const float* __restrict__ bout, float* __restrict__ out)
{
  const int b = blockIdx.x;
  const int lane = threadIdx.x;
  float p = 0.f;
  for (int j = lane; j < 384; j += 64) {
    float v = outs[(size_t)b * 384 + j];
    v = v > 0.f ? v : 0.f;
    p = fmaf(v, Wout[j], p);
  }
#pragma unroll
  for (int m = 32; m; m >>= 1) p += __shfl_xor(p, m, 64);
  if (lane == 0) {
    const float t = p + bout[0];
    out[b] = 1.f / (1.f + expf(-t));
  }
}

extern "C" void kernel_launch(void* const* d_in, const int* in_sizes, int n_in,
                              void* d_out, int out_size, void* d_ws, size_t ws_size,
                              hipStream_t stream)
{
  const float* x    = (const float*)d_in[0];
  const float* W0   = (const float*)d_in[1];
  const float* b0   = (const float*)d_in[2];
  const float* W1   = (const float*)d_in[3];
  const float* b1   = (const float*)d_in[4];
  const float* W2   = (const float*)d_in[5];
  const float* b2   = (const float*)d_in[6];
  const float* Wout = (const float*)d_in[7];
  const float* bout = (const float*)d_in[8];
  float* out = (float*)d_out;

  char* ws = (char*)d_ws;
  unsigned short* hT1  = (unsigned short*)ws;                    // 16 MB (hi+lo)
  unsigned short* hT2  = (unsigned short*)(ws + (16 << 20));     // 16 MB
  float*          outs = (float*)        (ws + (32 << 20));      // 768 KB
  unsigned short* Wi0  = (unsigned short*)(ws + (33 << 20));               // 512 KB
  unsigned short* Wi1  = (unsigned short*)(ws + (33 << 20) + (1 << 19));   // 2 MB
  unsigned short* Wi2  = (unsigned short*)(ws + (33 << 20) + (1 << 19) + (2 << 20)); // 2 MB

  // nthreads = (#chunks) * KSP * 512 = K/32 * 512
  repack_w_kernel<<<64,  256, 0, stream>>>(W0, Wi0, 32,  1, 16384);
  repack_w_kernel<<<256, 256, 0, stream>>>(W1, Wi1, 128, 2, 65536);
  repack_w_kernel<<<256, 256, 0, stream>>>(W2, Wi2, 128, 2, 65536);

  cin_mfma_layer<32,  1, 1, true,  true ><<<256, 512, 0, stream>>>(Wi0, x, nullptr, b0, hT1, outs, 0);
  cin_mfma_layer<128, 2, 2, false, true ><<<256, 512, 0, stream>>>(Wi1, x, hT1,    b1, hT2, outs, 128);
  cin_mfma_layer<128, 2, 2, false, false><<<256, 512, 0, stream>>>(Wi2, x, hT2,    b2, nullptr, outs, 256);

  cin_final_kernel<<<512, 64, 0, stream>>>(outs, Wout, bout, out);
}

// Round 11
// 212.293 us; speedup vs baseline: 1.0826x; 1.0826x over previous
//
#include <hip/hip_runtime.h>
#include <math.h>

// CIN (xDeepFM) — split-bf16 16x16x32 MFMA, all-VGPR working set.
// y[b,o,d] = bias[o] + sum_f x[b,f,d] * ( sum_h W[o,f*H+h] * h_in[b,h,d] )
//   W*h ~= Whi*hhi + Whi*hlo + Wlo*hhi   (split bf16, lo*lo dropped)
// KSP=1: chunk = one (pass,f) K=32 slice (16 KB, hi+lo planes). 1 batch/block,
// 8 waves, wave w owns o in [16w,16w+16). Live regs ~100 -> no AGPR pressure,
// no hidden v_accvgpr moves. 4-buffer LDS ring, 3-deep chunk prefetch,
// 1-deep register prefetch of A-fragments + x-scales. Wave-private staging ->
// no hot-loop barriers; per-wave counted vmcnt only (steady 4; tail 4/2/0/0).
// B=512, F=32, D=64, O=128; H0=32 (h=x), H1=H2=128; NPASS=H/32.

typedef __attribute__((ext_vector_type(8))) short bf16x8;
typedef __attribute__((ext_vector_type(4))) float f32x4;
typedef __attribute__((ext_vector_type(4))) unsigned short u16x4;

#define HT_LO 4194304   // shorts: 512*64*128 (offset of lo plane)

__device__ __forceinline__ unsigned short f2bf(float f) {
  unsigned int u = __float_as_uint(f);
  u = (u + 0x7fffu + ((u >> 16) & 1u)) >> 16;   // RNE
  return (unsigned short)u;
}
__device__ __forceinline__ float bf2f(unsigned short h) {
  return __uint_as_float((unsigned int)h << 16);
}

__device__ __forceinline__ void gll16(const void* g, void* l) {
  __builtin_amdgcn_global_load_lds(
      (const __attribute__((address_space(1))) unsigned int*)g,
      (__attribute__((address_space(3))) unsigned int*)l, 16, 0, 0);
}

// ---- pre-pass: repack W (fp32, row-major 128xK) into split-bf16 image,
// chunk-sequential in ITERATION order: chunk c = pass*32 + f at offset c*16KB.
// in-chunk (16B units): [s in {hi,lo}][idx = mt*64 + lane]
// element: W[o = mt*16+(l&15)][kcol = f*H + pass*32 + (l>>4)*8 + j]
__global__ void repack_w_kernel(const float* __restrict__ W, unsigned short* __restrict__ dst,
                                int H, int nthreads)
{
  const int t = blockIdx.x * 256 + threadIdx.x;
  if (t >= nthreads) return;
  const int K = 32 * H;
  const int idx = t & 511;
  const int c   = t >> 9;
  const int pass = c >> 5, f = c & 31;
  const int mt = idx >> 6, l = idx & 63;
  const int o = mt * 16 + (l & 15);
  const int kcol = f * H + pass * 32 + ((l >> 4) & 3) * 8;
  const float* s = W + (size_t)o * K + kcol;
  u16x4 h0, h1, l0, l1;
#pragma unroll
  for (int j = 0; j < 4; ++j) {
    float v = s[j];
    unsigned short hb = f2bf(v);
    h0[j] = hb; l0[j] = f2bf(v - bf2f(hb));
    v = s[4 + j];
    hb = f2bf(v);
    h1[j] = hb; l1[j] = f2bf(v - bf2f(hb));
  }
  const size_t uhi = (size_t)c * 1024 + idx;         // 16B units
  const size_t ulo = (size_t)c * 1024 + 512 + idx;
  *(u16x4*)(dst + uhi * 8)     = h0;
  *(u16x4*)(dst + uhi * 8 + 4) = h1;
  *(u16x4*)(dst + ulo * 8)     = l0;
  *(u16x4*)(dst + ulo * 8 + 4) = l1;
}

// one stage: prefetch chunk C+3 -> counted wait (chunk C+1 landed) ->
// reg-read A(C+1)/scales(C+1) (no wait) -> 12 MFMA with A(C) regs -> Y update.
#define BODY(C, BUF, DOPREF, WAITN, DOREAD)                                                \
  {                                                                                        \
    if (DOPREF) {                                                                          \
      const char* psrc = (const char*)Wimg + (size_t)((C) + 3) * 16384;                    \
      _Pragma("unroll")                                                                    \
      for (int r = 0; r < 2; ++r)                                                          \
        gll16(psrc + (size_t)(r * 512 + tid) * 16,                                         \
              lds + (((BUF) + 3) & 3) * 16384 + (r * 512 + w * 64) * 16);                  \
    }                                                                                      \
    asm volatile("s_waitcnt vmcnt(%0)" :: "i"(WAITN) : "memory");                          \
    if (DOREAD) {                                                                          \
      const char* nb = lds + (((BUF) + 1) & 3) * 16384;                                    \
      AH[((C) + 1) & 1] = *(const bf16x8*)(nb + ((0 * 8 + w) * 64 + l) * 16);              \
      AL[((C) + 1) & 1] = *(const bf16x8*)(nb + ((1 * 8 + w) * 64 + l) * 16);              \
      const int f1_ = ((C) + 1) & 31;                                                      \
      _Pragma("unroll")                                                                    \
      for (int nt = 0; nt < 4; ++nt)                                                       \
        Sv[((C) + 1) & 1][nt] = lx[f1_ * 64 + nt * 16 + li];                               \
    }                                                                                      \
    {                                                                                      \
      const bf16x8 Ah = AH[(C) & 1];                                                       \
      const bf16x8 Al = AL[(C) & 1];                                                       \
      f32x4 G[4];                                                                          \
      __builtin_amdgcn_s_setprio(1);                                                       \
      _Pragma("unroll")                                                                    \
      for (int nt = 0; nt < 4; ++nt) {                                                     \
        G[nt] = __builtin_amdgcn_mfma_f32_16x16x32_bf16(Ah, Bh[nt], zero4, 0, 0, 0);       \
        G[nt] = __builtin_amdgcn_mfma_f32_16x16x32_bf16(Ah, Bl[nt], G[nt], 0, 0, 0);       \
        G[nt] = __builtin_amdgcn_mfma_f32_16x16x32_bf16(Al, Bh[nt], G[nt], 0, 0, 0);       \
      }                                                                                    \
      __builtin_amdgcn_s_setprio(0);                                                       \
      _Pragma("unroll")                                                                    \
      for (int nt = 0; nt < 4; ++nt)                                                       \
        Y[nt] += G[nt] * Sv[(C) & 1][nt];                                                  \
    }                                                                                      \
  }

// ---- main layer kernel ----
// grid 512 x 512 threads; block = batch b; wave w owns o in [16w, 16w+16).
// LDS: [0, 64KB) = 4 x 16KB chunk ring; [64KB, +8KB) = raw x[b].
template<int H, int NPASS, bool FIRST, bool STORE_H>
__global__ __launch_bounds__(512, 4) void cin_mfma_layer(
    const unsigned short* __restrict__ Wimg,
    const float* __restrict__ x,               // (B,32,64) fp32
    const unsigned short* __restrict__ hTin,   // hi plane; lo at +HT_LO  (null if FIRST)
    const float* __restrict__ bias,
    unsigned short* __restrict__ hTout,        // hi plane; lo at +HT_LO
    float* __restrict__ outs, int col_off)
{
  constexpr int NIT = NPASS * 32;
  constexpr int XOFF = 4 * 16384;
  __shared__ char lds[XOFF + 8192];
  const int tid = threadIdx.x;
  const int w = tid >> 6, l = tid & 63, g = l >> 4, li = l & 15;
  const int b = blockIdx.x;
  const float* lx = (const float*)(lds + XOFF);

  // prologue: stage x[b] (1 gll) + chunks 0,1,2 (6 gll), all lane-linear
  gll16(x + (size_t)b * 2048 + tid * 4, lds + XOFF + w * 1024);
#pragma unroll
  for (int c = 0; c < 3; ++c) {
    const char* src = (const char*)Wimg + (size_t)c * 16384;
#pragma unroll
    for (int r = 0; r < 2; ++r)
      gll16(src + (size_t)(r * 512 + tid) * 16,
            lds + c * 16384 + (r * 512 + w * 64) * 16);
  }

  f32x4 Y[4];
#pragma unroll
  for (int nt = 0; nt < 4; ++nt) Y[nt] = (f32x4){0.f, 0.f, 0.f, 0.f};
  const f32x4 zero4 = (f32x4){0.f, 0.f, 0.f, 0.f};
  bf16x8 Bh[4], Bl[4];
  bf16x8 AH[2], AL[2];      // ping-pong A-fragment slots (slot = c&1)
  float Sv[2][4];           // ping-pong x-scale slots

  // the ONLY barrier: x-tile (oldest load) complete -> publish to all waves
  asm volatile("s_waitcnt vmcnt(6)" ::: "memory");
  __builtin_amdgcn_s_barrier();

  if constexpr (FIRST) {
    // build split B-fragments from raw x in LDS (h == x; NPASS==1)
#pragma unroll
    for (int nt = 0; nt < 4; ++nt) {
      union { bf16x8 v; unsigned short u[8]; } th, tl;
#pragma unroll
      for (int j = 0; j < 8; ++j) {
        const float xv = lx[(g * 8 + j) * 64 + nt * 16 + li];
        const unsigned short hb = f2bf(xv);
        th.u[j] = hb; tl.u[j] = f2bf(xv - bf2f(hb));
      }
      Bh[nt] = th.v; Bl[nt] = tl.v;
    }
  }

  // pre-read A(0) and scales(0) into slot 0 (chunk 0 landed after vmcnt(4))
  asm volatile("s_waitcnt vmcnt(4)" ::: "memory");
  AH[0] = *(const bf16x8*)(lds + ((0 * 8 + w) * 64 + l) * 16);
  AL[0] = *(const bf16x8*)(lds + ((1 * 8 + w) * 64 + l) * 16);
#pragma unroll
  for (int nt = 0; nt < 4; ++nt) Sv[0][nt] = lx[nt * 16 + li];

  for (int pass = 0; pass < NPASS; ++pass) {
    if constexpr (!FIRST) {
      // B-fragments for this pass (h rows [pass*32, pass*32+32), reused over f)
#pragma unroll
      for (int nt = 0; nt < 4; ++nt) {
        const size_t off = (size_t)b * 8192 + (size_t)(nt * 16 + li) * 128
                         + pass * 32 + g * 8;
        Bh[nt] = *(const bf16x8*)(hTin + off);
        Bl[nt] = *(const bf16x8*)(hTin + HT_LO + off);
      }
    }
    const int cb = pass * 32;
    const int fomax = (pass == NPASS - 1) ? 28 : 32;
#pragma unroll 1
    for (int fo = 0; fo < fomax; fo += 4) {
      BODY(cb + fo + 0, 0, true, 4, true)
      BODY(cb + fo + 1, 1, true, 4, true)
      BODY(cb + fo + 2, 2, true, 4, true)
      BODY(cb + fo + 3, 3, true, 4, true)
    }
  }
  // tail: last 4 chunks; waits ensure chunk C+1 in LDS before its reg-read
  BODY(NIT - 4, 0, true,  4, true)    // issues chunk NIT-1 into buf 3
  BODY(NIT - 3, 1, false, 2, true)
  BODY(NIT - 2, 2, false, 0, true)
  BODY(NIT - 1, 3, false, 0, false)

  // ---- epilogue: bias, split-hT store, outs row-sums ----
  const f32x4 bv = *(const f32x4*)(bias + w * 16 + g * 4);
#pragma unroll
  for (int nt = 0; nt < 4; ++nt) Y[nt] += bv;

  if constexpr (STORE_H) {
#pragma unroll
    for (int nt = 0; nt < 4; ++nt) {
      const int d = nt * 16 + li;
      u16x4 ph, pl;
#pragma unroll
      for (int j = 0; j < 4; ++j) {
        const unsigned short hb = f2bf(Y[nt][j]);
        ph[j] = hb; pl[j] = f2bf(Y[nt][j] - bf2f(hb));
      }
      const size_t off = (size_t)b * 8192 + (size_t)d * 128 + w * 16 + g * 4;
      *(u16x4*)(hTout + off)         = ph;
      *(u16x4*)(hTout + HT_LO + off) = pl;
    }
  }

  {
    f32x4 s = Y[0] + Y[1] + Y[2] + Y[3];
#pragma unroll
    for (int m = 1; m < 16; m <<= 1) {
      s.x += __shfl_xor(s.x, m, 16);
      s.y += __shfl_xor(s.y, m, 16);
      s.z += __shfl_xor(s.z, m, 16);
      s.w += __shfl_xor(s.w, m, 16);
    }
    if (li == 0)
      *(f32x4*)(outs + (size_t)b * 384 + col_off + w * 16 + g * 4) = s;
  }
}

// ---- final: out[b] = sigmoid( relu(outs[b,:]) . Wout + bout ) ----
__global__ __launch_bounds__(64) void cin_final_kernel(
    const float* __restrict__ outs, const float* __restrict__ Wout,
    const float* __restrict__ bout, float* __restrict__ out)
{
  const int b = blockIdx.x;
  const int lane = threadIdx.x;
  float p = 0.f;
  for (int j = lane; j < 384; j += 64) {
    float v = outs[(size_t)b * 384 + j];
    v = v > 0.f ? v : 0.f;
    p = fmaf(v, Wout[j], p);
  }
#pragma unroll
  for (int m = 32; m; m >>= 1) p += __shfl_xor(p, m, 64);
  if (lane == 0) {
    const float t = p + bout[0];
    out[b] = 1.f / (1.f + expf(-t));
  }
}

extern "C" void kernel_launch(void* const* d_in, const int* in_sizes, int n_in,
                              void* d_out, int out_size, void* d_ws, size_t ws_size,
                              hipStream_t stream)
{
  const float* x    = (const float*)d_in[0];
  const float* W0   = (const float*)d_in[1];
  const float* b0   = (const float*)d_in[2];
  const float* W1   = (const float*)d_in[3];
  const float* b1   = (const float*)d_in[4];
  const float* W2   = (const float*)d_in[5];
  const float* b2   = (const float*)d_in[6];
  const float* Wout = (const float*)d_in[7];
  const float* bout = (const float*)d_in[8];
  float* out = (float*)d_out;

  char* ws = (char*)d_ws;
  unsigned short* hT1  = (unsigned short*)ws;                    // 16 MB (hi+lo)
  unsigned short* hT2  = (unsigned short*)(ws + (16 << 20));     // 16 MB
  float*          outs = (float*)        (ws + (32 << 20));      // 768 KB
  unsigned short* Wi0  = (unsigned short*)(ws + (33 << 20));               // 512 KB
  unsigned short* Wi1  = (unsigned short*)(ws + (33 << 20) + (1 << 19));   // 2 MB
  unsigned short* Wi2  = (unsigned short*)(ws + (33 << 20) + (1 << 19) + (2 << 20)); // 2 MB

  // nthreads = (K/32 chunks) * 512
  repack_w_kernel<<<64,  256, 0, stream>>>(W0, Wi0, 32,  16384);
  repack_w_kernel<<<256, 256, 0, stream>>>(W1, Wi1, 128, 65536);
  repack_w_kernel<<<256, 256, 0, stream>>>(W2, Wi2, 128, 65536);

  cin_mfma_layer<32,  1, true,  true ><<<512, 512, 0, stream>>>(Wi0, x, nullptr, b0, hT1, outs, 0);
  cin_mfma_layer<128, 4, false, true ><<<512, 512, 0, stream>>>(Wi1, x, hT1,    b1, hT2, outs, 128);
  cin_mfma_layer<128, 4, false, false><<<512, 512, 0, stream>>>(Wi2, x, hT2,    b2, nullptr, outs, 256);

  cin_final_kernel<<<512, 64, 0, stream>>>(outs, Wout, bout, out);
}